// Round 10
// baseline (224.998 us; speedup 1.0000x reference)
//
#include <hip/hip_runtime.h>
#include <hip/hip_bf16.h>

// ============================================================================
// B=512, M=40, D=64. Three bilinear layers (200 outputs each):
//   out[o,d] = relu(bias[o] + sum_c W[o,c]*U[c,d]), U[(m,n),d] = x[m,d]*h[n,d]
// R10: 32x32x16 MFMA formulation, ZERO K-loop barriers.
//   Per b: C[224,64] = W'[224,K'] x U[K',64], K' = 40*NPAD (NPAD=40 / 104).
//   B-frag for 32x32x16: lane l holds B[k = 8*(l>>5)+e][n = l&31] -> 8
//   k-consecutive U elems at ONE column d = 32*nh + (l&31): built in-register
//   from 1 swizzled ds_read_b128 of h[n0..n0+7, d] + 1 x scalar (8 mul+4 pk).
//   No U staging, no build/consume barriers; hs/xs read-only during a layer.
// Block = 2 batches, 512 thr = 8 waves: wn = wv&1 (batch), gm = wv>>1 owns
//   m-tiles {0,1}/{2,3}/{4,5}/{6} of 32 rows; each wave covers BOTH col
//   halves (nh=0,1) -> rowsum completes in-wave (no psum).
// h layout: hs[pp][bb][d][128], elem n at pos 8*((n>>3)^(d&7)) + (n&7)
//   -> b128 reads conflict-free (4 dw/bank min, lanes l/l+32 broadcast).
// W repacked (prepass) frag-contiguous for 32x32 A layout: lane l holds
//   W'[32mt+(l&31)][32s+16j+8*(l>>5)..+8]; mt=6 stored COMPACT (8 real rows)
//   so pack = 3,968,000 B <= proven ws bound 3,993,600 B.
// ============================================================================

typedef float f32x16 __attribute__((ext_vector_type(16)));
typedef short bf16x8 __attribute__((ext_vector_type(8)));
typedef unsigned int uint;

struct LDS32 {
    float          xf[2][64][41];       // [bb][d][m] f32       20992 B
    __hip_bfloat16 xs[2][64][64];       // [bb][d][swz(m)]      16384 B
    __hip_bfloat16 hs[2][2][64][128];   // [pp][bb][d][swz(n)]  65536 B
};                                      // total 102912 B -> 1 block/CU

static __device__ __forceinline__ float bflo(uint u) {
    uint v = u << 16; return __builtin_bit_cast(float, v);
}
static __device__ __forceinline__ float bfhi(uint u) {
    uint v = u & 0xffff0000u; return __builtin_bit_cast(float, v);
}
static __device__ __forceinline__ uint pk_bf16(float a, float b) {
    uint r; asm("v_cvt_pk_bf16_f32 %0, %1, %2" : "=v"(r) : "v"(a), "v"(b));
    return r;
}
static __device__ __forceinline__ bf16x8 mkf(float x, uint4 h) {
    union { uint u[4]; bf16x8 v; } r;
    r.u[0] = pk_bf16(x * bflo(h.x), x * bfhi(h.x));
    r.u[1] = pk_bf16(x * bflo(h.y), x * bfhi(h.y));
    r.u[2] = pk_bf16(x * bflo(h.z), x * bfhi(h.z));
    r.u[3] = pk_bf16(x * bflo(h.w), x * bfhi(h.w));
    return r.v;
}

// ---------------------------------------------------------------------------
// One layer. T = m-tiles this wave owns (2 or 1). CP = compact A pack (mt6).
// ---------------------------------------------------------------------------
template<int NPAD, int NK, int HROW, int HASH, int ROWLO, int ROWOFF, int T, int CP>
__device__ __forceinline__ void layer32(
    const __hip_bfloat16* __restrict__ hbase, const float* __restrict__ xfw,
    __hip_bfloat16* __restrict__ hdst,
    const bf16x8* __restrict__ pwf, const bf16x8* __restrict__ pwc,
    const float* __restrict__ bias, float* __restrict__ outb,
    int lane, int mt0)
{
    const int l31 = lane & 31, h5 = lane >> 5, swz = lane & 7;
    const __hip_bfloat16* hr0 = hbase + l31 * HROW;          // nh=0 row d=l31
    const __hip_bfloat16* hr1 = hbase + (l31 + 32) * HROW;   // nh=1 row d=l31+32
    const float* xr0 = xfw + l31 * 41;
    const float* xr1 = xfw + (l31 + 32) * 41;

    const bool act  = (l31 < 8);          // compact-pack active lanes
    const int  slot = l31 + 8 * h5;

    const bf16x8* pA[T];
    #pragma unroll
    for (int t = 0; t < T; ++t)
        pA[t] = pwf + (size_t)(mt0 + t) * NK * 2 * 64 + lane;
    const bf16x8* pC = pwc + slot;

    const f32x16 zz = {0,0,0,0,0,0,0,0,0,0,0,0,0,0,0,0};
    f32x16 acc[T][2];
    #pragma unroll
    for (int t = 0; t < T; ++t) { acc[t][0] = zz; acc[t][1] = zz; }

    // per-lane (m, n) state for the two j-streams (k halves of a kstep)
    int n0 = 8 * h5,      m0 = 0;
    int n1 = 16 + 8 * h5, m1 = 0;

    auto loadA = [&](bf16x8 (*f)[2], int s) {
        if (s < NK) {
            if (CP) {
                if (act) {
                    f[0][0] = pC[(s * 2 + 0) * 16];
                    f[0][1] = pC[(s * 2 + 1) * 16];
                }
            } else {
                #pragma unroll
                for (int t = 0; t < T; ++t) {
                    f[t][0] = pA[t][(s * 2 + 0) * 64];
                    f[t][1] = pA[t][(s * 2 + 1) * 64];
                }
            }
        }
    };

    auto kstep = [&](bf16x8 (*f)[2]) {
        uint4 h00 = *(const uint4*)(hr0 + 8 * ((n0 >> 3) ^ swz));
        uint4 h01 = *(const uint4*)(hr0 + 8 * ((n1 >> 3) ^ swz));
        uint4 h10 = *(const uint4*)(hr1 + 8 * ((n0 >> 3) ^ swz));
        uint4 h11 = *(const uint4*)(hr1 + 8 * ((n1 >> 3) ^ swz));
        float x00 = xr0[m0], x01 = xr0[m1];
        float x10 = xr1[m0], x11 = xr1[m1];
        bf16x8 b00 = mkf(x00, h00);
        bf16x8 b01 = mkf(x01, h01);
        bf16x8 b10 = mkf(x10, h10);
        bf16x8 b11 = mkf(x11, h11);
        #pragma unroll
        for (int t = 0; t < T; ++t) {
            acc[t][0] = __builtin_amdgcn_mfma_f32_32x32x16_bf16(f[t][0], b00, acc[t][0], 0, 0, 0);
            acc[t][0] = __builtin_amdgcn_mfma_f32_32x32x16_bf16(f[t][1], b01, acc[t][0], 0, 0, 0);
            acc[t][1] = __builtin_amdgcn_mfma_f32_32x32x16_bf16(f[t][0], b10, acc[t][1], 0, 0, 0);
            acc[t][1] = __builtin_amdgcn_mfma_f32_32x32x16_bf16(f[t][1], b11, acc[t][1], 0, 0, 0);
        }
        n0 += 32; if (n0 >= NPAD) { n0 -= NPAD; ++m0; }
        n1 += 32; if (n1 >= NPAD) { n1 -= NPAD; ++m1; }
    };

    bf16x8 fa[T][2], fb[T][2];
    if (CP) {  // zero-init so inactive lanes contribute zero A rows
        union { uint u[4]; bf16x8 v; } fz; fz.u[0]=fz.u[1]=fz.u[2]=fz.u[3]=0u;
        #pragma unroll
        for (int t = 0; t < T; ++t) {
            fa[t][0]=fz.v; fa[t][1]=fz.v; fb[t][0]=fz.v; fb[t][1]=fz.v;
        }
    }
    loadA(fa, 0);
    loadA(fb, 1);

    #pragma unroll 1
    for (int s = 0; s < NK; s += 2) {       // NK even (50 / 130)
        kstep(fa);
        loadA(fa, s + 2);
        kstep(fb);
        loadA(fb, s + 3);
    }

    // ---- epilogue: 32x32 C/D layout (m74/m101-verified):
    //      col = lane&31, row = (reg&3) + 8*(reg>>2) + 4*(lane>>5) ----
    __hip_bfloat16* hd0 = hdst + l31 * 128;
    __hip_bfloat16* hd1 = hdst + (l31 + 32) * 128;
    #pragma unroll
    for (int t = 0; t < T; ++t) {
        #pragma unroll
        for (int reg = 0; reg < 16; ++reg) {
            const int o = 32 * (mt0 + t) + (reg & 3) + 8 * (reg >> 2) + 4 * h5;
            const float bs = bias[o < 200 ? o : 0];
            float r0 = fmaxf(acc[t][0][reg] + bs, 0.f);   // col d = l31
            float r1 = fmaxf(acc[t][1][reg] + bs, 0.f);   // col d = l31+32
            if (HASH && o < 100) {
                const int pos = 8 * ((o >> 3) ^ swz) + (o & 7);
                hd0[pos] = __float2bfloat16(r0);
                hd1[pos] = __float2bfloat16(r1);
            }
            float sv = r0 + r1;                            // both col halves
            sv += __shfl_xor(sv, 1, 64);
            sv += __shfl_xor(sv, 2, 64);
            sv += __shfl_xor(sv, 4, 64);
            sv += __shfl_xor(sv, 8, 64);
            sv += __shfl_xor(sv, 16, 64);
            if (l31 == 0 && o >= ROWLO && o < 200)
                outb[ROWOFF + (o - ROWLO)] = sv;
        }
    }
}

template<int T, int CP>
__device__ __forceinline__ void run_layers32(
    const __hip_bfloat16* xsw, const float* xfw,
    __hip_bfloat16* h1w, __hip_bfloat16* h2w,
    const bf16x8* w1f, const bf16x8* w2f, const bf16x8* w3f,
    const bf16x8* w1c, const bf16x8* w2c, const bf16x8* w3c,
    const float* b1, const float* b2, const float* b3,
    float* outb, int lane, int mt0)
{
    layer32< 40,  50,  64, 1, 100,   0, T, CP>(xsw, xfw, h1w, w1f, w1c, b1, outb, lane, mt0);
    __syncthreads();
    layer32<104, 130, 128, 1, 100, 100, T, CP>(h1w, xfw, h2w, w2f, w2c, b2, outb, lane, mt0);
    __syncthreads();
    layer32<104, 130, 128, 0,   0, 200, T, CP>(h2w, xfw, h2w, w3f, w3c, b3, outb, lane, mt0);
}

__global__ __launch_bounds__(512, 1)
void fused_mfma32(const float* __restrict__ x, const bf16x8* __restrict__ wp,
                  const float* __restrict__ b1, const float* __restrict__ b2,
                  const float* __restrict__ b3, float* __restrict__ out)
{
    __shared__ LDS32 L;
    const int tid = threadIdx.x, bi = blockIdx.x;

    // zero hs (NPAD region safety: W' is zero there, but h must not be NaN)
    uint4 z; z.x = z.y = z.z = z.w = 0u;
    uint4* hz = (uint4*)&L.hs[0][0][0][0];
    for (int i = tid; i < 4096; i += 512) hz[i] = z;

    // stage x (2 batches): f32 -> xf (f32, [d][m]) and xs (bf16, swizzled)
    const float* xg = x + (size_t)(2 * bi) * 2560;
    for (int i = tid; i < 5120; i += 512) {
        int bb = (i >= 2560) ? 1 : 0;
        int r  = i - bb * 2560;
        int m  = r >> 6, d = r & 63;
        float v = xg[i];
        L.xf[bb][d][m] = v;
        L.xs[bb][d][8 * ((m >> 3) ^ (d & 7)) + (m & 7)] = __float2bfloat16(v);
    }
    __syncthreads();

    const int lane = tid & 63, wv = tid >> 6;
    const int wn = wv & 1, gm = wv >> 1;
    float* outb = out + (size_t)(2 * bi + wn) * 400;

    const bf16x8* w1f = wp;                 // 6*50*2*64   = 38400 frags
    const bf16x8* w2f = wp + 38400;         // 6*130*2*64  = 99840
    const bf16x8* w3f = wp + 138240;        // 99840
    const bf16x8* w1c = wp + 238080;        // 50*2*16     = 1600
    const bf16x8* w2c = wp + 239680;        // 130*2*16    = 4160
    const bf16x8* w3c = wp + 243840;        // 4160  (end 248000)

    const float* xfw = &L.xf[wn][0][0];
    const __hip_bfloat16* xsw = &L.xs[wn][0][0];
    __hip_bfloat16* h1w = &L.hs[0][wn][0][0];
    __hip_bfloat16* h2w = &L.hs[1][wn][0][0];

    if (gm < 3)
        run_layers32<2, 0>(xsw, xfw, h1w, h2w, w1f, w2f, w3f, w1c, w2c, w3c,
                           b1, b2, b3, outb, lane, 2 * gm);
    else
        run_layers32<1, 1>(xsw, xfw, h1w, h2w, w1f, w2f, w3f, w1c, w2c, w3c,
                           b1, b2, b3, outb, lane, 6);
}

// ---------------------------------------------------------------------------
// Prepass: W fp32 -> bf16, 32x32-frag-contiguous, n padded to NPAD.
// Full frags (mt 0..5): idx = ((mt*NK + s)*2 + j)*64 + lane; lane holds
//   W'[32mt+(lane&31)][32s+16j+8*(lane>>5)..+8].
// Compact (mt=6, rows 192..199): idx = ((s*2+j)*16 + slot), slot = (l&7)+8*(l>>5),
//   row = 192+(slot&7), khalf = slot>>3.
// W'[row][c]: m = c/NPAD, n = c%NPAD; value = W[row][m*DIV+n] if n<DIV else 0.
// ---------------------------------------------------------------------------
__global__ void convert_pack32(const float* __restrict__ w1, const float* __restrict__ w2,
                               const float* __restrict__ w3, uint4* __restrict__ outp) {
    int c = blockIdx.x * 256 + threadIdx.x;
    if (c >= 248000) return;
    const float* src; int NK, DIV, NPAD, idx; bool compact;
    if (c < 38400)       { src = w1; NK = 50;  DIV = 40;  NPAD = 40;  idx = c;          compact = false; }
    else if (c < 138240) { src = w2; NK = 130; DIV = 100; NPAD = 104; idx = c - 38400;  compact = false; }
    else if (c < 238080) { src = w3; NK = 130; DIV = 100; NPAD = 104; idx = c - 138240; compact = false; }
    else if (c < 239680) { src = w1; NK = 50;  DIV = 40;  NPAD = 40;  idx = c - 238080; compact = true; }
    else if (c < 243840) { src = w2; NK = 130; DIV = 100; NPAD = 104; idx = c - 239680; compact = true; }
    else                 { src = w3; NK = 130; DIV = 100; NPAD = 104; idx = c - 243840; compact = true; }

    int row, m, n0;
    if (!compact) {
        int lane = idx & 63;
        int fj   = idx >> 6;
        int j    = fj & 1;
        int t2   = fj >> 1;            // mt*NK + s
        int mt   = t2 / NK;
        int s    = t2 - mt * NK;
        row = 32 * mt + (lane & 31);
        int c0 = 32 * s + 16 * j + 8 * (lane >> 5);
        m = c0 / NPAD; n0 = c0 - m * NPAD;
    } else {
        int slot = idx & 15;
        int sj   = idx >> 4;
        int j    = sj & 1;
        int s    = sj >> 1;
        row = 192 + (slot & 7);
        int c0 = 32 * s + 16 * j + 8 * (slot >> 3);
        m = c0 / NPAD; n0 = c0 - m * NPAD;
    }
    uint o[4];
    if (row < 200) {
        const float* p = src + (size_t)row * (40 * DIV) + m * DIV + n0;
        #pragma unroll
        for (int jj = 0; jj < 4; ++jj) {
            float flo = (n0 + 2 * jj     < DIV) ? p[2 * jj]     : 0.f;
            float fhi = (n0 + 2 * jj + 1 < DIV) ? p[2 * jj + 1] : 0.f;
            __hip_bfloat16 lo = __float2bfloat16(flo);
            __hip_bfloat16 hi = __float2bfloat16(fhi);
            o[jj] = (uint)__builtin_bit_cast(unsigned short, lo)
                  | ((uint)__builtin_bit_cast(unsigned short, hi) << 16);
        }
    } else {
        #pragma unroll
        for (int jj = 0; jj < 4; ++jj) o[jj] = 0u;
    }
    uint4 v; v.x = o[0]; v.y = o[1]; v.z = o[2]; v.w = o[3];
    outp[c] = v;
}

// ---------------------------------------------------------------------------
// Fallback (fp32 VALU kernel) if ws too small.
// ---------------------------------------------------------------------------
__global__ __launch_bounds__(512, 1)
void fused_bilinear_kernel(const float* __restrict__ x,
                           const float* __restrict__ w1, const float* __restrict__ b1,
                           const float* __restrict__ w2, const float* __restrict__ b2,
                           const float* __restrict__ w3, const float* __restrict__ b3,
                           float* __restrict__ out) {
    const int b   = blockIdx.x;
    const int tid = threadIdx.x;
    const int d   = tid & 63;
    const int wv  = tid >> 6;

    __shared__ float xs[40][64];
    __shared__ float hs[100][64];

    const float* xb = x + (size_t)b * 40 * 64;
    for (int i = tid; i < 40 * 64; i += 512) ((float*)xs)[i] = xb[i];
    __syncthreads();

    float xr[40];
    #pragma unroll
    for (int m = 0; m < 40; ++m) xr[m] = xs[m][d];
    float hr[100];
    const int o0 = __builtin_amdgcn_readfirstlane(wv * 25);

    for (int oi = 0; oi < 25; ++oi) {
        const int o = o0 + oi;
        const float* __restrict__ wrow = w1 + (size_t)o * 1600;
        float s = b1[o];
        for (int m = 0; m < 40; ++m) {
            const float* __restrict__ wm = wrow + m * 40;
            float a0 = 0.f, a1 = 0.f, a2 = 0.f, a3 = 0.f;
            #pragma unroll
            for (int n = 0; n < 40; n += 4) {
                a0 = fmaf(wm[n + 0], xr[n + 0], a0);
                a1 = fmaf(wm[n + 1], xr[n + 1], a1);
                a2 = fmaf(wm[n + 2], xr[n + 2], a2);
                a3 = fmaf(wm[n + 3], xr[n + 3], a3);
            }
            s = fmaf(xs[m][d], (a0 + a1) + (a2 + a3), s);
        }
        s = fmaxf(s, 0.f);
        if (o < 100) hs[o][d] = s;
        else {
            float r = s;
            #pragma unroll
            for (int off = 32; off > 0; off >>= 1) r += __shfl_xor(r, off, 64);
            if (d == 0) out[(size_t)b * 400 + (o - 100)] = r;
        }
    }
    __syncthreads();
    #pragma unroll
    for (int n = 0; n < 100; ++n) hr[n] = hs[n][d];
    __syncthreads();

    for (int oi = 0; oi < 25; ++oi) {
        const int o = o0 + oi;
        const float* __restrict__ wrow = w2 + (size_t)o * 4000;
        float s = b2[o];
        for (int m = 0; m < 40; ++m) {
            const float* __restrict__ wm = wrow + m * 100;
            float a0 = 0.f, a1 = 0.f, a2 = 0.f, a3 = 0.f;
            #pragma unroll
            for (int n = 0; n < 100; n += 4) {
                a0 = fmaf(wm[n + 0], hr[n + 0], a0);
                a1 = fmaf(wm[n + 1], hr[n + 1], a1);
                a2 = fmaf(wm[n + 2], hr[n + 2], a2);
                a3 = fmaf(wm[n + 3], hr[n + 3], a3);
            }
            s = fmaf(xs[m][d], (a0 + a1) + (a2 + a3), s);
        }
        s = fmaxf(s, 0.f);
        if (o < 100) hs[o][d] = s;
        else {
            float r = s;
            #pragma unroll
            for (int off = 32; off > 0; off >>= 1) r += __shfl_xor(r, off, 64);
            if (d == 0) out[(size_t)b * 400 + 100 + (o - 100)] = r;
        }
    }
    __syncthreads();
    #pragma unroll
    for (int n = 0; n < 100; ++n) hr[n] = hs[n][d];

    for (int oi = 0; oi < 25; ++oi) {
        const int o = o0 + oi;
        const float* __restrict__ wrow = w3 + (size_t)o * 4000;
        float s = b3[o];
        for (int m = 0; m < 40; ++m) {
            const float* __restrict__ wm = wrow + m * 100;
            float a0 = 0.f, a1 = 0.f, a2 = 0.f, a3 = 0.f;
            #pragma unroll
            for (int n = 0; n < 100; n += 4) {
                a0 = fmaf(wm[n + 0], hr[n + 0], a0);
                a1 = fmaf(wm[n + 1], hr[n + 1], a1);
                a2 = fmaf(wm[n + 2], hr[n + 2], a2);
                a3 = fmaf(wm[n + 3], hr[n + 3], a3);
            }
            s = fmaf(xs[m][d], (a0 + a1) + (a2 + a3), s);
        }
        s = fmaxf(s, 0.f);
        float r = s;
        #pragma unroll
        for (int off = 32; off > 0; off >>= 1) r += __shfl_xor(r, off, 64);
        if (d == 0) out[(size_t)b * 400 + 200 + o] = r;
    }
}

extern "C" void kernel_launch(void* const* d_in, const int* in_sizes, int n_in,
                              void* d_out, int out_size, void* d_ws, size_t ws_size,
                              hipStream_t stream) {
    const float* x  = (const float*)d_in[0];
    const float* w1 = (const float*)d_in[1];
    const float* b1 = (const float*)d_in[2];
    const float* w2 = (const float*)d_in[3];
    const float* b2 = (const float*)d_in[4];
    const float* w3 = (const float*)d_in[5];
    const float* b3 = (const float*)d_in[6];
    float* out = (float*)d_out;

    if (ws_size >= 248000u * 16u) {       // 3,968,000 B <= proven ws bound
        uint4* wp = (uint4*)d_ws;
        convert_pack32<<<dim3(969), dim3(256), 0, stream>>>(w1, w2, w3, wp);
        fused_mfma32<<<dim3(256), dim3(512), 0, stream>>>(
            x, (const bf16x8*)wp, b1, b2, b3, out);
    } else {
        fused_bilinear_kernel<<<dim3(512), dim3(512), 0, stream>>>(
            x, w1, b1, w2, b2, w3, b3, out);
    }
}